// Round 1
// baseline (8720.367 us; speedup 1.0000x reference)
//
#include <hip/hip_runtime.h>
#include <hip/hip_bf16.h>

#define ND 128
#define LDO 512
#define ALPHA 0.2f
#define L2EPS 1e-12f

// ---------------- copy embeddings into out[:, 0:128] ----------------
__global__ void copy_emb_kernel(const float* __restrict__ emb, float* __restrict__ out, int n) {
    int idx = blockIdx.x * blockDim.x + threadIdx.x;
    int total = n * 32;                       // n rows * 32 float4 per row
    if (idx >= total) return;
    int r = idx >> 5, c4 = idx & 31;
    const float4 v = *reinterpret_cast<const float4*>(emb + (size_t)r * ND + c4 * 4);
    *reinterpret_cast<float4*>(out + (size_t)r * LDO + c4 * 4) = v;
}

// ---------------- SPMM: Lx[r] += val[e] * x[col[e]] ----------------
// 32 lanes per edge, each lane handles 4 floats (float4 gather + 4 atomics)
__global__ void spmm_kernel(const int* __restrict__ erow, const int* __restrict__ ecol,
                            const float* __restrict__ eval, const float* __restrict__ x,
                            float* __restrict__ Lx, int n_edges) {
    int gid = blockIdx.x * blockDim.x + threadIdx.x;
    int e = gid >> 5;
    if (e >= n_edges) return;
    int l = gid & 31;
    int r = erow[e], c = ecol[e];
    float v = eval[e];
    const float4 xv = *reinterpret_cast<const float4*>(x + (size_t)c * LDO + l * 4);
    float* dst = Lx + (size_t)r * ND + l * 4;
    atomicAdd(dst + 0, v * xv.x);
    atomicAdd(dst + 1, v * xv.y);
    atomicAdd(dst + 2, v * xv.z);
    atomicAdd(dst + 3, v * xv.w);
}

// ---------------- fused layer: GEMM(prop,Wgc) + GEMM(x*Lx,Wbi) + bias + leaky + l2norm ----
// block = 256 threads, tile = 64 rows x 128 cols, K=128
__global__ __launch_bounds__(256) void fused_layer_kernel(
        const float* __restrict__ xin,   // out + i*128, row stride LDO
        const float* __restrict__ Lx,    // [n,128]
        const float* __restrict__ Wgc,   // [128,128]
        const float* __restrict__ bgc,   // [128]
        const float* __restrict__ Wbi,   // [128,128]
        const float* __restrict__ bbi,   // [128]
        float* __restrict__ xout,        // out + (i+1)*128, row stride LDO
        int n) {
    __shared__ float As_p[64][ND];   // prop = x + Lx      (32 KB)
    __shared__ float As_m[64][ND];   // xm   = x * Lx      (32 KB)
    __shared__ float Ws_g[16][ND];   // Wgc K-slice        (8 KB)
    __shared__ float Ws_b[16][ND];   // Wbi K-slice        (8 KB)

    const int tid = threadIdx.x;
    const int row0 = blockIdx.x * 64;

    // ---- stage A tile: 64 rows x 128 cols (prop and xm) ----
#pragma unroll
    for (int t = 0; t < 8; ++t) {
        int idx = tid + t * 256;          // 0..2047
        int r = idx >> 5;                 // 0..63
        int c4 = idx & 31;                // float4 index
        int grow = row0 + r;
        float4 xv = make_float4(0.f, 0.f, 0.f, 0.f);
        float4 lv = make_float4(0.f, 0.f, 0.f, 0.f);
        if (grow < n) {
            xv = *reinterpret_cast<const float4*>(xin + (size_t)grow * LDO + c4 * 4);
            lv = *reinterpret_cast<const float4*>(Lx + (size_t)grow * ND + c4 * 4);
        }
        float4 p = make_float4(xv.x + lv.x, xv.y + lv.y, xv.z + lv.z, xv.w + lv.w);
        float4 m = make_float4(xv.x * lv.x, xv.y * lv.y, xv.z * lv.z, xv.w * lv.w);
        *reinterpret_cast<float4*>(&As_p[r][c4 * 4]) = p;
        *reinterpret_cast<float4*>(&As_m[r][c4 * 4]) = m;
    }
    __syncthreads();

    const int tx = tid & 31;    // column group: cols tx*4 .. tx*4+3
    const int ty = tid >> 5;    // row group: rows ty*8 .. ty*8+7

    float4 acc[8];
#pragma unroll
    for (int r = 0; r < 8; ++r) acc[r] = make_float4(0.f, 0.f, 0.f, 0.f);

    for (int kk = 0; kk < 8; ++kk) {
        // stage W slice: k = kk*16 .. kk*16+15
#pragma unroll
        for (int t = 0; t < 2; ++t) {
            int idx = tid + t * 256;     // 0..511
            int k = idx >> 5, c4 = idx & 31;
            *reinterpret_cast<float4*>(&Ws_g[k][c4 * 4]) =
                *reinterpret_cast<const float4*>(Wgc + (size_t)(kk * 16 + k) * ND + c4 * 4);
            *reinterpret_cast<float4*>(&Ws_b[k][c4 * 4]) =
                *reinterpret_cast<const float4*>(Wbi + (size_t)(kk * 16 + k) * ND + c4 * 4);
        }
        __syncthreads();

#pragma unroll
        for (int k4 = 0; k4 < 4; ++k4) {
            float4 wg[4], wb[4];
#pragma unroll
            for (int k = 0; k < 4; ++k) {
                wg[k] = *reinterpret_cast<const float4*>(&Ws_g[k4 * 4 + k][tx * 4]);
                wb[k] = *reinterpret_cast<const float4*>(&Ws_b[k4 * 4 + k][tx * 4]);
            }
#pragma unroll
            for (int r = 0; r < 8; ++r) {
                float4 p = *reinterpret_cast<const float4*>(&As_p[ty * 8 + r][kk * 16 + k4 * 4]);
                float4 m = *reinterpret_cast<const float4*>(&As_m[ty * 8 + r][kk * 16 + k4 * 4]);
                float4 a = acc[r];
                a.x += p.x * wg[0].x + p.y * wg[1].x + p.z * wg[2].x + p.w * wg[3].x
                     + m.x * wb[0].x + m.y * wb[1].x + m.z * wb[2].x + m.w * wb[3].x;
                a.y += p.x * wg[0].y + p.y * wg[1].y + p.z * wg[2].y + p.w * wg[3].y
                     + m.x * wb[0].y + m.y * wb[1].y + m.z * wb[2].y + m.w * wb[3].y;
                a.z += p.x * wg[0].z + p.y * wg[1].z + p.z * wg[2].z + p.w * wg[3].z
                     + m.x * wb[0].z + m.y * wb[1].z + m.z * wb[2].z + m.w * wb[3].z;
                a.w += p.x * wg[0].w + p.y * wg[1].w + p.z * wg[2].w + p.w * wg[3].w
                     + m.x * wb[0].w + m.y * wb[1].w + m.z * wb[2].w + m.w * wb[3].w;
                acc[r] = a;
            }
        }
        __syncthreads();
    }

    // ---- epilogue: bias + leaky relu + row l2-normalize + store ----
    float4 bg = *reinterpret_cast<const float4*>(bgc + tx * 4);
    float4 bb = *reinterpret_cast<const float4*>(bbi + tx * 4);
    const float bx = bg.x + bb.x, by = bg.y + bb.y, bz = bg.z + bb.z, bw = bg.w + bb.w;

#pragma unroll
    for (int r = 0; r < 8; ++r) {
        int grow = row0 + ty * 8 + r;
        float x0 = acc[r].x + bx;
        float x1 = acc[r].y + by;
        float x2 = acc[r].z + bz;
        float x3 = acc[r].w + bw;
        x0 = x0 > 0.f ? x0 : ALPHA * x0;
        x1 = x1 > 0.f ? x1 : ALPHA * x1;
        x2 = x2 > 0.f ? x2 : ALPHA * x2;
        x3 = x3 > 0.f ? x3 : ALPHA * x3;
        float ssq = x0 * x0 + x1 * x1 + x2 * x2 + x3 * x3;
        // reduce across the 32 lanes sharing this row (same ty -> same 32-lane half)
#pragma unroll
        for (int off = 16; off >= 1; off >>= 1) ssq += __shfl_xor(ssq, off);
        float scale = 1.0f / sqrtf(fmaxf(ssq, L2EPS));
        if (grow < n) {
            float4 o = make_float4(x0 * scale, x1 * scale, x2 * scale, x3 * scale);
            *reinterpret_cast<float4*>(xout + (size_t)grow * LDO + tx * 4) = o;
        }
    }
}

extern "C" void kernel_launch(void* const* d_in, const int* in_sizes, int n_in,
                              void* d_out, int out_size, void* d_ws, size_t ws_size,
                              hipStream_t stream) {
    const float* emb  = (const float*)d_in[0];
    const int*   erow = (const int*)d_in[1];
    const int*   ecol = (const int*)d_in[2];
    const float* eval = (const float*)d_in[3];
    const float* Wgc  = (const float*)d_in[4];
    const float* bgc  = (const float*)d_in[5];
    const float* Wbi  = (const float*)d_in[6];
    const float* bbi  = (const float*)d_in[7];
    float* out = (float*)d_out;

    const int n       = in_sizes[0] / ND;       // 100000
    const int n_edges = in_sizes[1];            // 1600000
    const int n_layers = in_sizes[5] / ND;      // 3

    float* Lx = (float*)d_ws;                   // n*128 floats = 51.2 MB

    // x0 -> out[:, 0:128]
    {
        int total = n * 32;
        copy_emb_kernel<<<(total + 255) / 256, 256, 0, stream>>>(emb, out, n);
    }

    for (int i = 0; i < n_layers; ++i) {
        hipMemsetAsync(Lx, 0, (size_t)n * ND * sizeof(float), stream);

        {
            long long total = (long long)n_edges * 32;
            int blocks = (int)((total + 255) / 256);
            spmm_kernel<<<blocks, 256, 0, stream>>>(erow, ecol, eval,
                                                    out + (size_t)i * ND, Lx, n_edges);
        }

        {
            int blocks = (n + 63) / 64;
            fused_layer_kernel<<<blocks, 256, 0, stream>>>(
                out + (size_t)i * ND, Lx,
                Wgc + (size_t)i * ND * ND, bgc + (size_t)i * ND,
                Wbi + (size_t)i * ND * ND, bbi + (size_t)i * ND,
                out + (size_t)(i + 1) * ND, n);
        }
    }
}

// Round 2
// 1175.838 us; speedup vs baseline: 7.4163x; 7.4163x over previous
//
#include <hip/hip_runtime.h>
#include <hip/hip_bf16.h>

#define ND 128
#define LDO 512
#define ALPHA 0.2f
#define L2EPS 1e-12f
#define SCAN_B 256

// ---------------- copy embeddings into out[:, 0:128] ----------------
__global__ void copy_emb_kernel(const float* __restrict__ emb, float* __restrict__ out, int n) {
    int idx = blockIdx.x * blockDim.x + threadIdx.x;
    int total = n * 32;                       // n rows * 32 float4 per row
    if (idx >= total) return;
    int r = idx >> 5, c4 = idx & 31;
    const float4 v = *reinterpret_cast<const float4*>(emb + (size_t)r * ND + c4 * 4);
    *reinterpret_cast<float4*>(out + (size_t)r * LDO + c4 * 4) = v;
}

// ---------------- CSR build ----------------
__global__ void hist_kernel(const int* __restrict__ erow, int* __restrict__ counts, int n_edges) {
    int e = blockIdx.x * blockDim.x + threadIdx.x;
    if (e < n_edges) atomicAdd(&counts[erow[e]], 1);
}

// block-level exclusive scan of counts -> row_start (local part), block sums -> partials
__global__ __launch_bounds__(SCAN_B) void scanA_kernel(const int* __restrict__ counts,
                                                       int* __restrict__ row_start,
                                                       int* __restrict__ partials, int n) {
    __shared__ int sm[SCAN_B];
    int i = blockIdx.x * SCAN_B + threadIdx.x;
    int v = (i < n) ? counts[i] : 0;
    sm[threadIdx.x] = v;
    __syncthreads();
#pragma unroll
    for (int off = 1; off < SCAN_B; off <<= 1) {
        int t = (threadIdx.x >= off) ? sm[threadIdx.x - off] : 0;
        __syncthreads();
        sm[threadIdx.x] += t;
        __syncthreads();
    }
    if (i < n) row_start[i] = sm[threadIdx.x] - v;      // exclusive local prefix
    if (threadIdx.x == SCAN_B - 1) partials[blockIdx.x] = sm[SCAN_B - 1];
}

// single-block exclusive scan of partials (nb <= 512)
__global__ __launch_bounds__(512) void scanB_kernel(int* __restrict__ partials, int nb) {
    __shared__ int sm[512];
    int v = (threadIdx.x < nb) ? partials[threadIdx.x] : 0;
    sm[threadIdx.x] = v;
    __syncthreads();
#pragma unroll
    for (int off = 1; off < 512; off <<= 1) {
        int t = (threadIdx.x >= off) ? sm[threadIdx.x - off] : 0;
        __syncthreads();
        sm[threadIdx.x] += t;
        __syncthreads();
    }
    if (threadIdx.x < nb) partials[threadIdx.x] = sm[threadIdx.x] - v;  // exclusive
}

// add block offsets, produce final row_start + cursor copy; row_start[n] = n_edges
__global__ void scanC_kernel(int* __restrict__ row_start, const int* __restrict__ partials,
                             int* __restrict__ cursor, int n, int n_edges) {
    int i = blockIdx.x * blockDim.x + threadIdx.x;
    if (i < n) {
        int v = row_start[i] + partials[i >> 8];
        row_start[i] = v;
        cursor[i] = v;
    } else if (i == n) {
        row_start[n] = n_edges;
    }
}

__global__ void scatter_kernel(const int* __restrict__ erow, const int* __restrict__ ecol,
                               const float* __restrict__ eval, int* __restrict__ cursor,
                               int* __restrict__ col_s, float* __restrict__ val_s, int n_edges) {
    int e = blockIdx.x * blockDim.x + threadIdx.x;
    if (e >= n_edges) return;
    int pos = atomicAdd(&cursor[erow[e]], 1);
    col_s[pos] = ecol[e];
    val_s[pos] = eval[e];
}

// ---------------- pull-mode CSR SPMM: Lx[r] = sum val * x[col] ----------------
// 32 lanes per row (float4 per lane), 8 rows per 256-thread block
__global__ __launch_bounds__(256) void spmm_csr_kernel(const int* __restrict__ row_start,
                                                       const int* __restrict__ col_s,
                                                       const float* __restrict__ val_s,
                                                       const float* __restrict__ x,
                                                       float* __restrict__ Lx, int n) {
    int r = blockIdx.x * 8 + (threadIdx.x >> 5);
    if (r >= n) return;
    int l = threadIdx.x & 31;
    int s = row_start[r], e = row_start[r + 1];
    float4 acc = make_float4(0.f, 0.f, 0.f, 0.f);
    int j = s;
    for (; j + 1 < e; j += 2) {
        float v0 = val_s[j],     v1 = val_s[j + 1];
        int   c0 = col_s[j],     c1 = col_s[j + 1];
        float4 x0 = *reinterpret_cast<const float4*>(x + (size_t)c0 * LDO + l * 4);
        float4 x1 = *reinterpret_cast<const float4*>(x + (size_t)c1 * LDO + l * 4);
        acc.x += v0 * x0.x + v1 * x1.x;
        acc.y += v0 * x0.y + v1 * x1.y;
        acc.z += v0 * x0.z + v1 * x1.z;
        acc.w += v0 * x0.w + v1 * x1.w;
    }
    if (j < e) {
        float v0 = val_s[j];
        int   c0 = col_s[j];
        float4 x0 = *reinterpret_cast<const float4*>(x + (size_t)c0 * LDO + l * 4);
        acc.x += v0 * x0.x; acc.y += v0 * x0.y; acc.z += v0 * x0.z; acc.w += v0 * x0.w;
    }
    *reinterpret_cast<float4*>(Lx + (size_t)r * ND + l * 4) = acc;
}

// ---------------- fused layer: GEMM(prop,Wgc) + GEMM(x*Lx,Wbi) + bias + leaky + l2norm ----
__global__ __launch_bounds__(256) void fused_layer_kernel(
        const float* __restrict__ xin,   // out + i*128, row stride LDO
        const float* __restrict__ Lx,    // [n,128]
        const float* __restrict__ Wgc,   // [128,128]
        const float* __restrict__ bgc,   // [128]
        const float* __restrict__ Wbi,   // [128,128]
        const float* __restrict__ bbi,   // [128]
        float* __restrict__ xout,        // out + (i+1)*128, row stride LDO
        int n) {
    __shared__ float As_p[64][ND];   // prop = x + Lx      (32 KB)
    __shared__ float As_m[64][ND];   // xm   = x * Lx      (32 KB)
    __shared__ float Ws_g[16][ND];   // Wgc K-slice        (8 KB)
    __shared__ float Ws_b[16][ND];   // Wbi K-slice        (8 KB)

    const int tid = threadIdx.x;
    const int row0 = blockIdx.x * 64;

#pragma unroll
    for (int t = 0; t < 8; ++t) {
        int idx = tid + t * 256;
        int r = idx >> 5;
        int c4 = idx & 31;
        int grow = row0 + r;
        float4 xv = make_float4(0.f, 0.f, 0.f, 0.f);
        float4 lv = make_float4(0.f, 0.f, 0.f, 0.f);
        if (grow < n) {
            xv = *reinterpret_cast<const float4*>(xin + (size_t)grow * LDO + c4 * 4);
            lv = *reinterpret_cast<const float4*>(Lx + (size_t)grow * ND + c4 * 4);
        }
        float4 p = make_float4(xv.x + lv.x, xv.y + lv.y, xv.z + lv.z, xv.w + lv.w);
        float4 m = make_float4(xv.x * lv.x, xv.y * lv.y, xv.z * lv.z, xv.w * lv.w);
        *reinterpret_cast<float4*>(&As_p[r][c4 * 4]) = p;
        *reinterpret_cast<float4*>(&As_m[r][c4 * 4]) = m;
    }
    __syncthreads();

    const int tx = tid & 31;
    const int ty = tid >> 5;

    float4 acc[8];
#pragma unroll
    for (int r = 0; r < 8; ++r) acc[r] = make_float4(0.f, 0.f, 0.f, 0.f);

    for (int kk = 0; kk < 8; ++kk) {
#pragma unroll
        for (int t = 0; t < 2; ++t) {
            int idx = tid + t * 256;
            int k = idx >> 5, c4 = idx & 31;
            *reinterpret_cast<float4*>(&Ws_g[k][c4 * 4]) =
                *reinterpret_cast<const float4*>(Wgc + (size_t)(kk * 16 + k) * ND + c4 * 4);
            *reinterpret_cast<float4*>(&Ws_b[k][c4 * 4]) =
                *reinterpret_cast<const float4*>(Wbi + (size_t)(kk * 16 + k) * ND + c4 * 4);
        }
        __syncthreads();

#pragma unroll
        for (int k4 = 0; k4 < 4; ++k4) {
            float4 wg[4], wb[4];
#pragma unroll
            for (int k = 0; k < 4; ++k) {
                wg[k] = *reinterpret_cast<const float4*>(&Ws_g[k4 * 4 + k][tx * 4]);
                wb[k] = *reinterpret_cast<const float4*>(&Ws_b[k4 * 4 + k][tx * 4]);
            }
#pragma unroll
            for (int r = 0; r < 8; ++r) {
                float4 p = *reinterpret_cast<const float4*>(&As_p[ty * 8 + r][kk * 16 + k4 * 4]);
                float4 m = *reinterpret_cast<const float4*>(&As_m[ty * 8 + r][kk * 16 + k4 * 4]);
                float4 a = acc[r];
                a.x += p.x * wg[0].x + p.y * wg[1].x + p.z * wg[2].x + p.w * wg[3].x
                     + m.x * wb[0].x + m.y * wb[1].x + m.z * wb[2].x + m.w * wb[3].x;
                a.y += p.x * wg[0].y + p.y * wg[1].y + p.z * wg[2].y + p.w * wg[3].y
                     + m.x * wb[0].y + m.y * wb[1].y + m.z * wb[2].y + m.w * wb[3].y;
                a.z += p.x * wg[0].z + p.y * wg[1].z + p.z * wg[2].z + p.w * wg[3].z
                     + m.x * wb[0].z + m.y * wb[1].z + m.z * wb[2].z + m.w * wb[3].z;
                a.w += p.x * wg[0].w + p.y * wg[1].w + p.z * wg[2].w + p.w * wg[3].w
                     + m.x * wb[0].w + m.y * wb[1].w + m.z * wb[2].w + m.w * wb[3].w;
                acc[r] = a;
            }
        }
        __syncthreads();
    }

    float4 bg = *reinterpret_cast<const float4*>(bgc + tx * 4);
    float4 bb = *reinterpret_cast<const float4*>(bbi + tx * 4);
    const float bx = bg.x + bb.x, by = bg.y + bb.y, bz = bg.z + bb.z, bw = bg.w + bb.w;

#pragma unroll
    for (int r = 0; r < 8; ++r) {
        int grow = row0 + ty * 8 + r;
        float x0 = acc[r].x + bx;
        float x1 = acc[r].y + by;
        float x2 = acc[r].z + bz;
        float x3 = acc[r].w + bw;
        x0 = x0 > 0.f ? x0 : ALPHA * x0;
        x1 = x1 > 0.f ? x1 : ALPHA * x1;
        x2 = x2 > 0.f ? x2 : ALPHA * x2;
        x3 = x3 > 0.f ? x3 : ALPHA * x3;
        float ssq = x0 * x0 + x1 * x1 + x2 * x2 + x3 * x3;
#pragma unroll
        for (int off = 16; off >= 1; off >>= 1) ssq += __shfl_xor(ssq, off);
        float scale = 1.0f / sqrtf(fmaxf(ssq, L2EPS));
        if (grow < n) {
            float4 o = make_float4(x0 * scale, x1 * scale, x2 * scale, x3 * scale);
            *reinterpret_cast<float4*>(xout + (size_t)grow * LDO + tx * 4) = o;
        }
    }
}

extern "C" void kernel_launch(void* const* d_in, const int* in_sizes, int n_in,
                              void* d_out, int out_size, void* d_ws, size_t ws_size,
                              hipStream_t stream) {
    const float* emb  = (const float*)d_in[0];
    const int*   erow = (const int*)d_in[1];
    const int*   ecol = (const int*)d_in[2];
    const float* eval = (const float*)d_in[3];
    const float* Wgc  = (const float*)d_in[4];
    const float* bgc  = (const float*)d_in[5];
    const float* Wbi  = (const float*)d_in[6];
    const float* bbi  = (const float*)d_in[7];
    float* out = (float*)d_out;

    const int n        = in_sizes[0] / ND;      // 100000
    const int n_edges  = in_sizes[1];           // 1600000
    const int n_layers = in_sizes[5] / ND;      // 3

    // ---- workspace layout (256B-aligned) ----
    char* ws = (char*)d_ws;
    size_t off = 0;
    auto alloc = [&](size_t bytes) { void* p = ws + off; off = (off + bytes + 255) & ~(size_t)255; return p; };
    float* Lx        = (float*)alloc((size_t)n * ND * sizeof(float));     // 51.2 MB
    int*   col_s     = (int*)  alloc((size_t)n_edges * sizeof(int));      // 6.4 MB
    float* val_s     = (float*)alloc((size_t)n_edges * sizeof(float));    // 6.4 MB
    int*   counts    = (int*)  alloc((size_t)n * sizeof(int));
    int*   row_start = (int*)  alloc((size_t)(n + 1) * sizeof(int));
    int*   cursor    = (int*)  alloc((size_t)n * sizeof(int));
    int*   partials  = (int*)  alloc(512 * sizeof(int));
    (void)ws_size;

    // ---- x0 -> out[:, 0:128] ----
    {
        int total = n * 32;
        copy_emb_kernel<<<(total + 255) / 256, 256, 0, stream>>>(emb, out, n);
    }

    // ---- CSR build ----
    hipMemsetAsync(counts, 0, (size_t)n * sizeof(int), stream);
    hist_kernel<<<(n_edges + 255) / 256, 256, 0, stream>>>(erow, counts, n_edges);
    int nblk = (n + SCAN_B - 1) / SCAN_B;                       // 391
    scanA_kernel<<<nblk, SCAN_B, 0, stream>>>(counts, row_start, partials, n);
    scanB_kernel<<<1, 512, 0, stream>>>(partials, nblk);
    scanC_kernel<<<(n + 1 + 255) / 256, 256, 0, stream>>>(row_start, partials, cursor, n, n_edges);
    scatter_kernel<<<(n_edges + 255) / 256, 256, 0, stream>>>(erow, ecol, eval, cursor,
                                                              col_s, val_s, n_edges);

    // ---- layers ----
    for (int i = 0; i < n_layers; ++i) {
        spmm_csr_kernel<<<(n + 7) / 8, 256, 0, stream>>>(row_start, col_s, val_s,
                                                         out + (size_t)i * ND, Lx, n);
        fused_layer_kernel<<<(n + 63) / 64, 256, 0, stream>>>(
            out + (size_t)i * ND, Lx,
            Wgc + (size_t)i * ND * ND, bgc + (size_t)i * ND,
            Wbi + (size_t)i * ND * ND, bbi + (size_t)i * ND,
            out + (size_t)(i + 1) * ND, n);
    }
}

// Round 3
// 655.514 us; speedup vs baseline: 13.3031x; 1.7938x over previous
//
#include <hip/hip_runtime.h>
#include <hip/hip_bf16.h>

#define ND 128
#define LDO 512
#define ALPHA 0.2f
#define L2EPS 1e-12f
#define SCAN_B 256

typedef __attribute__((ext_vector_type(8))) short short8;
typedef __attribute__((ext_vector_type(4))) float f32x4;

__device__ __forceinline__ short f2bf(float f) {
    union { float f; unsigned u; } c; c.f = f;
    unsigned u = c.u;
    unsigned r = (u + 0x7fffu + ((u >> 16) & 1u)) >> 16;   // RNE
    return (short)r;
}

// ---------------- copy embeddings into out[:, 0:128] ----------------
__global__ void copy_emb_kernel(const float* __restrict__ emb, float* __restrict__ out, int n) {
    int idx = blockIdx.x * blockDim.x + threadIdx.x;
    int total = n * 32;
    if (idx >= total) return;
    int r = idx >> 5, c4 = idx & 31;
    const float4 v = *reinterpret_cast<const float4*>(emb + (size_t)r * ND + c4 * 4);
    *reinterpret_cast<float4*>(out + (size_t)r * LDO + c4 * 4) = v;
}

// ---------------- CSR build ----------------
__global__ void hist_kernel(const int* __restrict__ erow, int* __restrict__ counts, int n_edges) {
    int e = blockIdx.x * blockDim.x + threadIdx.x;
    if (e < n_edges) atomicAdd(&counts[erow[e]], 1);
}

__global__ __launch_bounds__(SCAN_B) void scanA_kernel(const int* __restrict__ counts,
                                                       int* __restrict__ row_start,
                                                       int* __restrict__ partials, int n) {
    __shared__ int sm[SCAN_B];
    int i = blockIdx.x * SCAN_B + threadIdx.x;
    int v = (i < n) ? counts[i] : 0;
    sm[threadIdx.x] = v;
    __syncthreads();
#pragma unroll
    for (int off = 1; off < SCAN_B; off <<= 1) {
        int t = (threadIdx.x >= off) ? sm[threadIdx.x - off] : 0;
        __syncthreads();
        sm[threadIdx.x] += t;
        __syncthreads();
    }
    if (i < n) row_start[i] = sm[threadIdx.x] - v;
    if (threadIdx.x == SCAN_B - 1) partials[blockIdx.x] = sm[SCAN_B - 1];
}

__global__ __launch_bounds__(512) void scanB_kernel(int* __restrict__ partials, int nb) {
    __shared__ int sm[512];
    int v = (threadIdx.x < nb) ? partials[threadIdx.x] : 0;
    sm[threadIdx.x] = v;
    __syncthreads();
#pragma unroll
    for (int off = 1; off < 512; off <<= 1) {
        int t = (threadIdx.x >= off) ? sm[threadIdx.x - off] : 0;
        __syncthreads();
        sm[threadIdx.x] += t;
        __syncthreads();
    }
    if (threadIdx.x < nb) partials[threadIdx.x] = sm[threadIdx.x] - v;
}

__global__ void scanC_kernel(int* __restrict__ row_start, const int* __restrict__ partials,
                             int* __restrict__ cursor, int n, int n_edges) {
    int i = blockIdx.x * blockDim.x + threadIdx.x;
    if (i < n) {
        int v = row_start[i] + partials[i >> 8];
        row_start[i] = v;
        cursor[i] = v;
    } else if (i == n) {
        row_start[n] = n_edges;
    }
}

__global__ void scatter_kernel(const int* __restrict__ erow, const int* __restrict__ ecol,
                               const float* __restrict__ eval, int* __restrict__ cursor,
                               int* __restrict__ col_s, float* __restrict__ val_s, int n_edges) {
    int e = blockIdx.x * blockDim.x + threadIdx.x;
    if (e >= n_edges) return;
    int pos = atomicAdd(&cursor[erow[e]], 1);
    col_s[pos] = ecol[e];
    val_s[pos] = eval[e];
}

// ---------------- pull-mode CSR SPMM ----------------
__global__ __launch_bounds__(256) void spmm_csr_kernel(const int* __restrict__ row_start,
                                                       const int* __restrict__ col_s,
                                                       const float* __restrict__ val_s,
                                                       const float* __restrict__ x,
                                                       float* __restrict__ Lx, int n) {
    int r = blockIdx.x * 8 + (threadIdx.x >> 5);
    if (r >= n) return;
    int l = threadIdx.x & 31;
    int s = row_start[r], e = row_start[r + 1];
    float4 acc = make_float4(0.f, 0.f, 0.f, 0.f);
    int j = s;
    for (; j + 1 < e; j += 2) {
        float v0 = val_s[j],     v1 = val_s[j + 1];
        int   c0 = col_s[j],     c1 = col_s[j + 1];
        float4 x0 = *reinterpret_cast<const float4*>(x + (size_t)c0 * LDO + l * 4);
        float4 x1 = *reinterpret_cast<const float4*>(x + (size_t)c1 * LDO + l * 4);
        acc.x += v0 * x0.x + v1 * x1.x;
        acc.y += v0 * x0.y + v1 * x1.y;
        acc.z += v0 * x0.z + v1 * x1.z;
        acc.w += v0 * x0.w + v1 * x1.w;
    }
    if (j < e) {
        float v0 = val_s[j];
        int   c0 = col_s[j];
        float4 x0 = *reinterpret_cast<const float4*>(x + (size_t)c0 * LDO + l * 4);
        acc.x += v0 * x0.x; acc.y += v0 * x0.y; acc.z += v0 * x0.z; acc.w += v0 * x0.w;
    }
    *reinterpret_cast<float4*>(Lx + (size_t)r * ND + l * 4) = acc;
}

// ---------------- prep: Wt[layer][n][k] = bf16 of [Wgc;Wbi]^T, bsum = bgc+bbi ----------
// grid (n_layers, 128), 256 threads. Thread t<128: Wgc col read; t>=128: Wbi.
__global__ void prep_w_kernel(const float* __restrict__ Wgc, const float* __restrict__ bgc,
                              const float* __restrict__ Wbi, const float* __restrict__ bbi,
                              short* __restrict__ Wt, float* __restrict__ bsum) {
    int z = blockIdx.x;
    int k = blockIdx.y;            // 0..127
    int t = threadIdx.x;
    int nn = t & 127;
    const float* src = (t < 128) ? (Wgc + ((size_t)z * 128 + k) * 128)
                                 : (Wbi + ((size_t)z * 128 + k) * 128);
    float v = src[nn];
    int kk = (t < 128) ? k : (128 + k);
    Wt[(size_t)z * 128 * 256 + (size_t)nn * 256 + kk] = f2bf(v);
    if (k == 0 && t < 128) bsum[z * 128 + t] = bgc[z * 128 + t] + bbi[z * 128 + t];
}

// ---------------- fused layer via MFMA ----------------
// C = [prop | x*Lx] @ [Wgc; Wbi]  (K=256), then bias + leaky + row l2-norm.
// block = 256 thr (4 waves), tile = 64 rows x 128 cols; wave handles 16 rows.
// LDS: A (bf16, [64][256], XOR-swizzled) 32KB + W half (bf16, [128][128], swizzled) 32KB.
__global__ __launch_bounds__(256) void fused_layer_mfma(
        const float* __restrict__ xin,   // row stride LDO
        const float* __restrict__ Lx,    // row stride ND
        const short* __restrict__ Wt,    // [128][256] bf16 (W^T concat)
        const float* __restrict__ bsum,  // [128]
        float* __restrict__ xout,        // row stride LDO
        int n) {
    __shared__ short A_lds[64 * 256];    // 32 KB
    __shared__ short W_lds[128 * 128];   // 32 KB

    const int tid  = threadIdx.x;
    const int row0 = blockIdx.x * 64;
    const int lane = tid & 63;
    const int w    = tid >> 6;           // wave 0..3
    const int lrow = lane & 15;
    const int kgrp = lane >> 4;          // 0..3

    // ---- stage A = prop||xm, bf16, swizzled (kk ^= row&7 in 16B units) ----
#pragma unroll
    for (int t = 0; t < 4; ++t) {
        int idx = tid + t * 256;         // 0..1023
        int r   = idx >> 4;              // 0..63
        int ck  = idx & 15;              // 8-float chunk
        int grow = row0 + r;
        float4 xa = make_float4(0.f,0.f,0.f,0.f), xb = xa, la = xa, lb = xa;
        if (grow < n) {
            const float* xp = xin + (size_t)grow * LDO + ck * 8;
            xa = *reinterpret_cast<const float4*>(xp);
            xb = *reinterpret_cast<const float4*>(xp + 4);
            const float* lp = Lx + (size_t)grow * ND + ck * 8;
            la = *reinterpret_cast<const float4*>(lp);
            lb = *reinterpret_cast<const float4*>(lp + 4);
        }
        short8 pr, xm;
        pr[0]=f2bf(xa.x+la.x); pr[1]=f2bf(xa.y+la.y); pr[2]=f2bf(xa.z+la.z); pr[3]=f2bf(xa.w+la.w);
        pr[4]=f2bf(xb.x+lb.x); pr[5]=f2bf(xb.y+lb.y); pr[6]=f2bf(xb.z+lb.z); pr[7]=f2bf(xb.w+lb.w);
        xm[0]=f2bf(xa.x*la.x); xm[1]=f2bf(xa.y*la.y); xm[2]=f2bf(xa.z*la.z); xm[3]=f2bf(xa.w*la.w);
        xm[4]=f2bf(xb.x*lb.x); xm[5]=f2bf(xb.y*lb.y); xm[6]=f2bf(xb.z*lb.z); xm[7]=f2bf(xb.w*lb.w);
        int s = r & 7;
        *reinterpret_cast<short8*>(&A_lds[r * 256 + ((ck        ^ s) << 3)]) = pr;
        *reinterpret_cast<short8*>(&A_lds[r * 256 + (((16 + ck) ^ s) << 3)]) = xm;
    }

    f32x4 acc[8];
#pragma unroll
    for (int nf = 0; nf < 8; ++nf) acc[nf] = (f32x4){0.f, 0.f, 0.f, 0.f};

#pragma unroll
    for (int h = 0; h < 2; ++h) {
        if (h) __syncthreads();          // all reads of half 0 done before overwrite
        // ---- stage W half h: W_lds[nr][k] = Wt[nr][h*128 + k], swizzled ----
#pragma unroll
        for (int t = 0; t < 8; ++t) {
            int idx = tid + t * 256;     // 0..2047
            int nr  = idx >> 4;          // 0..127
            int kkl = idx & 15;
            short8 wv = *reinterpret_cast<const short8*>(&Wt[(size_t)nr * 256 + h * 128 + kkl * 8]);
            *reinterpret_cast<short8*>(&W_lds[nr * 128 + ((kkl ^ (nr & 7)) << 3)]) = wv;
        }
        __syncthreads();

        const int ar = w * 16 + lrow;
        const int as = ar & 7;
#pragma unroll
        for (int ksl = 0; ksl < 4; ++ksl) {
            int kk  = h * 16 + ksl * 4 + kgrp;          // A 16B-unit index (0..31)
            int kkl = ksl * 4 + kgrp;                   // W local unit (0..15)
            short8 af = *reinterpret_cast<const short8*>(&A_lds[ar * 256 + ((kk ^ as) << 3)]);
#pragma unroll
            for (int nf = 0; nf < 8; ++nf) {
                int nr = nf * 16 + lrow;
                short8 bfr = *reinterpret_cast<const short8*>(&W_lds[nr * 128 + ((kkl ^ (nr & 7)) << 3)]);
                acc[nf] = __builtin_amdgcn_mfma_f32_16x16x32_bf16(af, bfr, acc[nf], 0, 0, 0);
            }
        }
    }

    // ---- epilogue: bias + leaky + row l2-norm ----
    // C/D layout: col = nf*16 + lrow, row = kgrp*4 + reg (within wave's 16-row tile)
    float bsv[8];
#pragma unroll
    for (int nf = 0; nf < 8; ++nf) bsv[nf] = bsum[nf * 16 + lrow];

#pragma unroll
    for (int reg = 0; reg < 4; ++reg) {
        int grow = row0 + w * 16 + kgrp * 4 + reg;
        float v[8];
        float ssq = 0.f;
#pragma unroll
        for (int nf = 0; nf < 8; ++nf) {
            float tv = acc[nf][reg] + bsv[nf];
            tv = tv > 0.f ? tv : ALPHA * tv;
            v[nf] = tv;
            ssq += tv * tv;
        }
        ssq += __shfl_xor(ssq, 1);
        ssq += __shfl_xor(ssq, 2);
        ssq += __shfl_xor(ssq, 4);
        ssq += __shfl_xor(ssq, 8);
        float sc = 1.0f / sqrtf(fmaxf(ssq, L2EPS));
        if (grow < n) {
            float* op = xout + (size_t)grow * LDO;
#pragma unroll
            for (int nf = 0; nf < 8; ++nf) op[nf * 16 + lrow] = v[nf] * sc;
        }
    }
}

extern "C" void kernel_launch(void* const* d_in, const int* in_sizes, int n_in,
                              void* d_out, int out_size, void* d_ws, size_t ws_size,
                              hipStream_t stream) {
    const float* emb  = (const float*)d_in[0];
    const int*   erow = (const int*)d_in[1];
    const int*   ecol = (const int*)d_in[2];
    const float* eval = (const float*)d_in[3];
    const float* Wgc  = (const float*)d_in[4];
    const float* bgc  = (const float*)d_in[5];
    const float* Wbi  = (const float*)d_in[6];
    const float* bbi  = (const float*)d_in[7];
    float* out = (float*)d_out;

    const int n        = in_sizes[0] / ND;      // 100000
    const int n_edges  = in_sizes[1];           // 1600000
    const int n_layers = in_sizes[5] / ND;      // 3

    // ---- workspace layout (256B-aligned) ----
    char* ws = (char*)d_ws;
    size_t off = 0;
    auto alloc = [&](size_t bytes) { void* p = ws + off; off = (off + bytes + 255) & ~(size_t)255; return p; };
    float* Lx        = (float*)alloc((size_t)n * ND * sizeof(float));     // 51.2 MB
    int*   col_s     = (int*)  alloc((size_t)n_edges * sizeof(int));      // 6.4 MB
    float* val_s     = (float*)alloc((size_t)n_edges * sizeof(float));    // 6.4 MB
    int*   counts    = (int*)  alloc((size_t)n * sizeof(int));
    int*   row_start = (int*)  alloc((size_t)(n + 1) * sizeof(int));
    int*   cursor    = (int*)  alloc((size_t)n * sizeof(int));
    int*   partials  = (int*)  alloc(512 * sizeof(int));
    short* Wt        = (short*)alloc((size_t)n_layers * 128 * 256 * sizeof(short));
    float* bsum      = (float*)alloc((size_t)n_layers * 128 * sizeof(float));
    (void)ws_size;

    // ---- x0 -> out[:, 0:128] ----
    {
        int total = n * 32;
        copy_emb_kernel<<<(total + 255) / 256, 256, 0, stream>>>(emb, out, n);
    }

    // ---- weight prep (transpose + bf16 + bias sum) ----
    {
        dim3 g(n_layers, 128);
        prep_w_kernel<<<g, 256, 0, stream>>>(Wgc, bgc, Wbi, bbi, Wt, bsum);
    }

    // ---- CSR build ----
    hipMemsetAsync(counts, 0, (size_t)n * sizeof(int), stream);
    hist_kernel<<<(n_edges + 255) / 256, 256, 0, stream>>>(erow, counts, n_edges);
    int nblk = (n + SCAN_B - 1) / SCAN_B;
    scanA_kernel<<<nblk, SCAN_B, 0, stream>>>(counts, row_start, partials, n);
    scanB_kernel<<<1, 512, 0, stream>>>(partials, nblk);
    scanC_kernel<<<(n + 1 + 255) / 256, 256, 0, stream>>>(row_start, partials, cursor, n, n_edges);
    scatter_kernel<<<(n_edges + 255) / 256, 256, 0, stream>>>(erow, ecol, eval, cursor,
                                                              col_s, val_s, n_edges);

    // ---- layers ----
    for (int i = 0; i < n_layers; ++i) {
        spmm_csr_kernel<<<(n + 7) / 8, 256, 0, stream>>>(row_start, col_s, val_s,
                                                         out + (size_t)i * ND, Lx, n);
        fused_layer_mfma<<<(n + 63) / 64, 256, 0, stream>>>(
            out + (size_t)i * ND, Lx,
            Wt + (size_t)i * 128 * 256, bsum + (size_t)i * 128,
            out + (size_t)(i + 1) * ND, n);
    }
}

// Round 4
// 523.783 us; speedup vs baseline: 16.6488x; 1.2515x over previous
//
#include <hip/hip_runtime.h>
#include <hip/hip_bf16.h>

#define ND 128
#define LDO 512
#define ALPHA 0.2f
#define L2EPS 1e-12f
#define SCAN_B 256

typedef __attribute__((ext_vector_type(8))) short short8;
typedef __attribute__((ext_vector_type(4))) float f32x4;

__device__ __forceinline__ short f2bf(float f) {
    union { float f; unsigned u; } c; c.f = f;
    unsigned u = c.u;
    unsigned r = (u + 0x7fffu + ((u >> 16) & 1u)) >> 16;   // RNE
    return (short)r;
}
__device__ __forceinline__ float bf2f(unsigned short u) {
    union { unsigned u; float f; } c; c.u = ((unsigned)u) << 16;
    return c.f;
}

// ---------------- copy embeddings into out[:, 0:128] and xb ----------------
__global__ void copy_emb_kernel(const float* __restrict__ emb, float* __restrict__ out,
                                unsigned short* __restrict__ xb, int n) {
    int idx = blockIdx.x * blockDim.x + threadIdx.x;
    int total = n * 32;
    if (idx >= total) return;
    int r = idx >> 5, c4 = idx & 31;
    const float4 v = *reinterpret_cast<const float4*>(emb + (size_t)r * ND + c4 * 4);
    *reinterpret_cast<float4*>(out + (size_t)r * LDO + c4 * 4) = v;
    ushort4 b;
    b.x = (unsigned short)f2bf(v.x); b.y = (unsigned short)f2bf(v.y);
    b.z = (unsigned short)f2bf(v.z); b.w = (unsigned short)f2bf(v.w);
    *reinterpret_cast<ushort4*>(xb + (size_t)r * ND + c4 * 4) = b;
}

// ---------------- CSR build ----------------
__global__ void hist_kernel(const int* __restrict__ erow, int* __restrict__ counts, int n_edges) {
    int e = blockIdx.x * blockDim.x + threadIdx.x;
    if (e < n_edges) atomicAdd(&counts[erow[e]], 1);
}

__global__ __launch_bounds__(SCAN_B) void scanA_kernel(const int* __restrict__ counts,
                                                       int* __restrict__ row_start,
                                                       int* __restrict__ partials, int n) {
    __shared__ int sm[SCAN_B];
    int i = blockIdx.x * SCAN_B + threadIdx.x;
    int v = (i < n) ? counts[i] : 0;
    sm[threadIdx.x] = v;
    __syncthreads();
#pragma unroll
    for (int off = 1; off < SCAN_B; off <<= 1) {
        int t = (threadIdx.x >= off) ? sm[threadIdx.x - off] : 0;
        __syncthreads();
        sm[threadIdx.x] += t;
        __syncthreads();
    }
    if (i < n) row_start[i] = sm[threadIdx.x] - v;
    if (threadIdx.x == SCAN_B - 1) partials[blockIdx.x] = sm[SCAN_B - 1];
}

__global__ __launch_bounds__(512) void scanB_kernel(int* __restrict__ partials, int nb) {
    __shared__ int sm[512];
    int v = (threadIdx.x < nb) ? partials[threadIdx.x] : 0;
    sm[threadIdx.x] = v;
    __syncthreads();
#pragma unroll
    for (int off = 1; off < 512; off <<= 1) {
        int t = (threadIdx.x >= off) ? sm[threadIdx.x - off] : 0;
        __syncthreads();
        sm[threadIdx.x] += t;
        __syncthreads();
    }
    if (threadIdx.x < nb) partials[threadIdx.x] = sm[threadIdx.x] - v;
}

__global__ void scanC_kernel(int* __restrict__ row_start, const int* __restrict__ partials,
                             int* __restrict__ cursor, int n, int n_edges) {
    int i = blockIdx.x * blockDim.x + threadIdx.x;
    if (i < n) {
        int v = row_start[i] + partials[i >> 8];
        row_start[i] = v;
        cursor[i] = v;
    } else if (i == n) {
        row_start[n] = n_edges;
    }
}

__global__ void scatter_kernel(const int* __restrict__ erow, const int* __restrict__ ecol,
                               const float* __restrict__ eval, int* __restrict__ cursor,
                               int2* __restrict__ pv, int n_edges) {
    int e = blockIdx.x * blockDim.x + threadIdx.x;
    if (e >= n_edges) return;
    int pos = atomicAdd(&cursor[erow[e]], 1);
    int2 p;
    p.x = ecol[e];
    p.y = __float_as_int(eval[e]);
    pv[pos] = p;
}

// ---------------- pull-mode CSR SPMM (bf16 gather, bf16 out) ----------------
// 32 lanes per row (4 bf16 per lane), 8 rows per 256-thread block
__global__ __launch_bounds__(256) void spmm_csr_kernel(const int* __restrict__ row_start,
                                                       const int2* __restrict__ pv,
                                                       const unsigned short* __restrict__ xb,
                                                       unsigned short* __restrict__ Lxb, int n) {
    int r = blockIdx.x * 8 + (threadIdx.x >> 5);
    if (r >= n) return;
    int l = threadIdx.x & 31;
    int s = row_start[r], e = row_start[r + 1];
    float a0 = 0.f, a1 = 0.f, a2 = 0.f, a3 = 0.f;
    int j = s;
    for (; j + 1 < e; j += 2) {
        int2 p0 = pv[j], p1 = pv[j + 1];
        float v0 = __int_as_float(p0.y), v1 = __int_as_float(p1.y);
        ushort4 x0 = *reinterpret_cast<const ushort4*>(xb + (size_t)p0.x * ND + l * 4);
        ushort4 x1 = *reinterpret_cast<const ushort4*>(xb + (size_t)p1.x * ND + l * 4);
        a0 += v0 * bf2f(x0.x) + v1 * bf2f(x1.x);
        a1 += v0 * bf2f(x0.y) + v1 * bf2f(x1.y);
        a2 += v0 * bf2f(x0.z) + v1 * bf2f(x1.z);
        a3 += v0 * bf2f(x0.w) + v1 * bf2f(x1.w);
    }
    if (j < e) {
        int2 p0 = pv[j];
        float v0 = __int_as_float(p0.y);
        ushort4 x0 = *reinterpret_cast<const ushort4*>(xb + (size_t)p0.x * ND + l * 4);
        a0 += v0 * bf2f(x0.x);
        a1 += v0 * bf2f(x0.y);
        a2 += v0 * bf2f(x0.z);
        a3 += v0 * bf2f(x0.w);
    }
    ushort4 o;
    o.x = (unsigned short)f2bf(a0); o.y = (unsigned short)f2bf(a1);
    o.z = (unsigned short)f2bf(a2); o.w = (unsigned short)f2bf(a3);
    *reinterpret_cast<ushort4*>(Lxb + (size_t)r * ND + l * 4) = o;
}

// ---------------- prep: Wt[layer][n][k] = bf16 of [Wgc;Wbi]^T, bsum = bgc+bbi ----------
__global__ void prep_w_kernel(const float* __restrict__ Wgc, const float* __restrict__ bgc,
                              const float* __restrict__ Wbi, const float* __restrict__ bbi,
                              short* __restrict__ Wt, float* __restrict__ bsum) {
    int z = blockIdx.x;
    int k = blockIdx.y;
    int t = threadIdx.x;
    int nn = t & 127;
    const float* src = (t < 128) ? (Wgc + ((size_t)z * 128 + k) * 128)
                                 : (Wbi + ((size_t)z * 128 + k) * 128);
    float v = src[nn];
    int kk = (t < 128) ? k : (128 + k);
    Wt[(size_t)z * 128 * 256 + (size_t)nn * 256 + kk] = f2bf(v);
    if (k == 0 && t < 128) bsum[z * 128 + t] = bgc[z * 128 + t] + bbi[z * 128 + t];
}

// ---------------- fused layer via MFMA ----------------
__global__ __launch_bounds__(256) void fused_layer_mfma(
        const float* __restrict__ xin,            // row stride LDO (fp32)
        const unsigned short* __restrict__ Lxb,   // [n][128] bf16
        const short* __restrict__ Wt,             // [128][256] bf16 (W^T concat)
        const float* __restrict__ bsum,           // [128]
        float* __restrict__ xout,                 // row stride LDO (fp32)
        unsigned short* __restrict__ xbout,       // [n][128] bf16 shadow
        int n) {
    __shared__ short A_lds[64 * 256];    // 32 KB
    __shared__ short W_lds[128 * 128];   // 32 KB

    const int tid  = threadIdx.x;
    const int row0 = blockIdx.x * 64;
    const int lane = tid & 63;
    const int w    = tid >> 6;
    const int lrow = lane & 15;
    const int kgrp = lane >> 4;

    // ---- stage A = prop||xm, bf16, swizzled (16B units, ^ (row&7)) ----
#pragma unroll
    for (int t = 0; t < 4; ++t) {
        int idx = tid + t * 256;
        int r   = idx >> 4;              // 0..63
        int ck  = idx & 15;              // 8-elem chunk
        int grow = row0 + r;
        float4 xa = make_float4(0.f,0.f,0.f,0.f), xb4 = xa;
        float lf[8] = {0.f,0.f,0.f,0.f,0.f,0.f,0.f,0.f};
        if (grow < n) {
            const float* xp = xin + (size_t)grow * LDO + ck * 8;
            xa  = *reinterpret_cast<const float4*>(xp);
            xb4 = *reinterpret_cast<const float4*>(xp + 4);
            short8 lv = *reinterpret_cast<const short8*>(Lxb + (size_t)grow * ND + ck * 8);
#pragma unroll
            for (int q = 0; q < 8; ++q) lf[q] = bf2f((unsigned short)lv[q]);
        }
        short8 pr, xm;
        pr[0]=f2bf(xa.x+lf[0]); pr[1]=f2bf(xa.y+lf[1]); pr[2]=f2bf(xa.z+lf[2]); pr[3]=f2bf(xa.w+lf[3]);
        pr[4]=f2bf(xb4.x+lf[4]); pr[5]=f2bf(xb4.y+lf[5]); pr[6]=f2bf(xb4.z+lf[6]); pr[7]=f2bf(xb4.w+lf[7]);
        xm[0]=f2bf(xa.x*lf[0]); xm[1]=f2bf(xa.y*lf[1]); xm[2]=f2bf(xa.z*lf[2]); xm[3]=f2bf(xa.w*lf[3]);
        xm[4]=f2bf(xb4.x*lf[4]); xm[5]=f2bf(xb4.y*lf[5]); xm[6]=f2bf(xb4.z*lf[6]); xm[7]=f2bf(xb4.w*lf[7]);
        int s = r & 7;
        *reinterpret_cast<short8*>(&A_lds[r * 256 + ((ck        ^ s) << 3)]) = pr;
        *reinterpret_cast<short8*>(&A_lds[r * 256 + (((16 + ck) ^ s) << 3)]) = xm;
    }

    f32x4 acc[8];
#pragma unroll
    for (int nf = 0; nf < 8; ++nf) acc[nf] = (f32x4){0.f, 0.f, 0.f, 0.f};

#pragma unroll
    for (int h = 0; h < 2; ++h) {
        if (h) __syncthreads();
#pragma unroll
        for (int t = 0; t < 8; ++t) {
            int idx = tid + t * 256;
            int nr  = idx >> 4;
            int kkl = idx & 15;
            short8 wv = *reinterpret_cast<const short8*>(&Wt[(size_t)nr * 256 + h * 128 + kkl * 8]);
            *reinterpret_cast<short8*>(&W_lds[nr * 128 + ((kkl ^ (nr & 7)) << 3)]) = wv;
        }
        __syncthreads();

        const int ar = w * 16 + lrow;
        const int as = ar & 7;
#pragma unroll
        for (int ksl = 0; ksl < 4; ++ksl) {
            int kk  = h * 16 + ksl * 4 + kgrp;
            int kkl = ksl * 4 + kgrp;
            short8 af = *reinterpret_cast<const short8*>(&A_lds[ar * 256 + ((kk ^ as) << 3)]);
#pragma unroll
            for (int nf = 0; nf < 8; ++nf) {
                int nr = nf * 16 + lrow;
                short8 bfr = *reinterpret_cast<const short8*>(&W_lds[nr * 128 + ((kkl ^ (nr & 7)) << 3)]);
                acc[nf] = __builtin_amdgcn_mfma_f32_16x16x32_bf16(af, bfr, acc[nf], 0, 0, 0);
            }
        }
    }

    // ---- epilogue: bias + leaky + row l2-norm; write fp32 out + bf16 shadow ----
    float bsv[8];
#pragma unroll
    for (int nf = 0; nf < 8; ++nf) bsv[nf] = bsum[nf * 16 + lrow];

#pragma unroll
    for (int reg = 0; reg < 4; ++reg) {
        int grow = row0 + w * 16 + kgrp * 4 + reg;
        float v[8];
        float ssq = 0.f;
#pragma unroll
        for (int nf = 0; nf < 8; ++nf) {
            float tv = acc[nf][reg] + bsv[nf];
            tv = tv > 0.f ? tv : ALPHA * tv;
            v[nf] = tv;
            ssq += tv * tv;
        }
        ssq += __shfl_xor(ssq, 1);
        ssq += __shfl_xor(ssq, 2);
        ssq += __shfl_xor(ssq, 4);
        ssq += __shfl_xor(ssq, 8);
        float sc = 1.0f / sqrtf(fmaxf(ssq, L2EPS));
        if (grow < n) {
            float* op = xout + (size_t)grow * LDO;
            unsigned short* bp = xbout + (size_t)grow * ND;
#pragma unroll
            for (int nf = 0; nf < 8; ++nf) {
                float ov = v[nf] * sc;
                op[nf * 16 + lrow] = ov;
                bp[nf * 16 + lrow] = (unsigned short)f2bf(ov);
            }
        }
    }
}

extern "C" void kernel_launch(void* const* d_in, const int* in_sizes, int n_in,
                              void* d_out, int out_size, void* d_ws, size_t ws_size,
                              hipStream_t stream) {
    const float* emb  = (const float*)d_in[0];
    const int*   erow = (const int*)d_in[1];
    const int*   ecol = (const int*)d_in[2];
    const float* eval = (const float*)d_in[3];
    const float* Wgc  = (const float*)d_in[4];
    const float* bgc  = (const float*)d_in[5];
    const float* Wbi  = (const float*)d_in[6];
    const float* bbi  = (const float*)d_in[7];
    float* out = (float*)d_out;

    const int n        = in_sizes[0] / ND;      // 100000
    const int n_edges  = in_sizes[1];           // 1600000
    const int n_layers = in_sizes[5] / ND;      // 3

    // ---- workspace layout (256B-aligned) ----
    char* ws = (char*)d_ws;
    size_t off = 0;
    auto alloc = [&](size_t bytes) { void* p = ws + off; off = (off + bytes + 255) & ~(size_t)255; return p; };
    unsigned short* xb  = (unsigned short*)alloc((size_t)n * ND * sizeof(short));   // 25.6 MB
    unsigned short* Lxb = (unsigned short*)alloc((size_t)n * ND * sizeof(short));   // 25.6 MB
    int2*  pv        = (int2*) alloc((size_t)n_edges * sizeof(int2));               // 12.8 MB
    int*   counts    = (int*)  alloc((size_t)n * sizeof(int));
    int*   row_start = (int*)  alloc((size_t)(n + 1) * sizeof(int));
    int*   cursor    = (int*)  alloc((size_t)n * sizeof(int));
    int*   partials  = (int*)  alloc(512 * sizeof(int));
    short* Wt        = (short*)alloc((size_t)n_layers * 128 * 256 * sizeof(short));
    float* bsum      = (float*)alloc((size_t)n_layers * 128 * sizeof(float));
    (void)ws_size;

    // ---- x0 -> out[:, 0:128] + xb ----
    {
        int total = n * 32;
        copy_emb_kernel<<<(total + 255) / 256, 256, 0, stream>>>(emb, out, xb, n);
    }

    // ---- weight prep ----
    {
        dim3 g(n_layers, 128);
        prep_w_kernel<<<g, 256, 0, stream>>>(Wgc, bgc, Wbi, bbi, Wt, bsum);
    }

    // ---- CSR build ----
    hipMemsetAsync(counts, 0, (size_t)n * sizeof(int), stream);
    hist_kernel<<<(n_edges + 255) / 256, 256, 0, stream>>>(erow, counts, n_edges);
    int nblk = (n + SCAN_B - 1) / SCAN_B;
    scanA_kernel<<<nblk, SCAN_B, 0, stream>>>(counts, row_start, partials, n);
    scanB_kernel<<<1, 512, 0, stream>>>(partials, nblk);
    scanC_kernel<<<(n + 1 + 255) / 256, 256, 0, stream>>>(row_start, partials, cursor, n, n_edges);
    scatter_kernel<<<(n_edges + 255) / 256, 256, 0, stream>>>(erow, ecol, eval, cursor,
                                                              pv, n_edges);

    // ---- layers ----
    for (int i = 0; i < n_layers; ++i) {
        spmm_csr_kernel<<<(n + 7) / 8, 256, 0, stream>>>(row_start, pv, xb, Lxb, n);
        fused_layer_mfma<<<(n + 63) / 64, 256, 0, stream>>>(
            out + (size_t)i * ND, Lxb,
            Wt + (size_t)i * 128 * 256, bsum + (size_t)i * 128,
            out + (size_t)(i + 1) * ND, xb, n);
    }
}

// Round 5
// 448.943 us; speedup vs baseline: 19.4242x; 1.1667x over previous
//
#include <hip/hip_runtime.h>
#include <hip/hip_bf16.h>

#define ND 128
#define LDO 512
#define ALPHA 0.2f
#define L2EPS 1e-12f
#define SCAN_B 256
#define NCHUNK 256     // edge chunks for bucket hist/scatter
#define RPB 512        // rows per bucket (shift 9)

typedef __attribute__((ext_vector_type(8))) short short8;
typedef __attribute__((ext_vector_type(4))) float f32x4;

__device__ __forceinline__ short f2bf(float f) {
    union { float f; unsigned u; } c; c.f = f;
    unsigned u = c.u;
    unsigned r = (u + 0x7fffu + ((u >> 16) & 1u)) >> 16;   // RNE
    return (short)r;
}
__device__ __forceinline__ float bf2f(unsigned short u) {
    union { unsigned u; float f; } c; c.u = ((unsigned)u) << 16;
    return c.f;
}

// ---------------- copy embeddings into out[:, 0:128] and xb ----------------
__global__ void copy_emb_kernel(const float* __restrict__ emb, float* __restrict__ out,
                                unsigned short* __restrict__ xb, int n) {
    int idx = blockIdx.x * blockDim.x + threadIdx.x;
    int total = n * 32;
    if (idx >= total) return;
    int r = idx >> 5, c4 = idx & 31;
    const float4 v = *reinterpret_cast<const float4*>(emb + (size_t)r * ND + c4 * 4);
    *reinterpret_cast<float4*>(out + (size_t)r * LDO + c4 * 4) = v;
    ushort4 b;
    b.x = (unsigned short)f2bf(v.x); b.y = (unsigned short)f2bf(v.y);
    b.z = (unsigned short)f2bf(v.z); b.w = (unsigned short)f2bf(v.w);
    *reinterpret_cast<ushort4*>(xb + (size_t)r * ND + c4 * 4) = b;
}

// ---------------- pass A: per-chunk bucket histogram + per-row histogram ----------------
__global__ __launch_bounds__(256) void bucket_hist_kernel(const int* __restrict__ erow,
                                                          int* __restrict__ counts,
                                                          int* __restrict__ gcnt,
                                                          int n_edges, int nb, int ch) {
    __shared__ int cnt[256];
    int b = blockIdx.x;
    cnt[threadIdx.x] = 0;
    __syncthreads();
    int s = b * ch, e = min(n_edges, s + ch);
    for (int j = s + threadIdx.x; j < e; j += 256) {
        int r = erow[j];
        atomicAdd(&counts[r], 1);
        atomicAdd(&cnt[r >> 9], 1);
    }
    __syncthreads();
    for (int i = threadIdx.x; i < nb; i += 256) gcnt[i * NCHUNK + b] = cnt[i];
}

// ---------------- scans ----------------
__global__ __launch_bounds__(SCAN_B) void scanA_kernel(const int* __restrict__ in,
                                                       int* __restrict__ outp,
                                                       int* __restrict__ partials, int n) {
    __shared__ int sm[SCAN_B];
    int i = blockIdx.x * SCAN_B + threadIdx.x;
    int v = (i < n) ? in[i] : 0;
    sm[threadIdx.x] = v;
    __syncthreads();
#pragma unroll
    for (int off = 1; off < SCAN_B; off <<= 1) {
        int t = (threadIdx.x >= off) ? sm[threadIdx.x - off] : 0;
        __syncthreads();
        sm[threadIdx.x] += t;
        __syncthreads();
    }
    if (i < n) outp[i] = sm[threadIdx.x] - v;
    if (threadIdx.x == SCAN_B - 1) partials[blockIdx.x] = sm[SCAN_B - 1];
}

__global__ __launch_bounds__(512) void scanB_kernel(int* __restrict__ partials, int nb) {
    __shared__ int sm[512];
    int v = (threadIdx.x < nb) ? partials[threadIdx.x] : 0;
    sm[threadIdx.x] = v;
    __syncthreads();
#pragma unroll
    for (int off = 1; off < 512; off <<= 1) {
        int t = (threadIdx.x >= off) ? sm[threadIdx.x - off] : 0;
        __syncthreads();
        sm[threadIdx.x] += t;
        __syncthreads();
    }
    if (threadIdx.x < nb) partials[threadIdx.x] = sm[threadIdx.x] - v;
}

__global__ void scan_add_kernel(int* __restrict__ arr, const int* __restrict__ partials,
                                int n, int sentinel_val, int set_sentinel) {
    int i = blockIdx.x * blockDim.x + threadIdx.x;
    if (i < n) arr[i] += partials[i >> 8];
    else if (set_sentinel && i == n) arr[n] = sentinel_val;
}

// ---------------- pass B: scatter into bucket-grouped tmp (coalesced runs) ----------------
__global__ __launch_bounds__(256) void bucket_scatter_kernel(const int* __restrict__ erow,
                                                             const int* __restrict__ ecol,
                                                             const float* __restrict__ eval,
                                                             const int* __restrict__ gbase,
                                                             int2* __restrict__ tmp,
                                                             int n_edges, int nb, int ch) {
    __shared__ int cur[256];
    int b = blockIdx.x;
    for (int i = threadIdx.x; i < nb; i += 256) cur[i] = gbase[i * NCHUNK + b];
    __syncthreads();
    int s = b * ch, e = min(n_edges, s + ch);
    for (int j = s + threadIdx.x; j < e; j += 256) {
        int r = erow[j];
        int pos = atomicAdd(&cur[r >> 9], 1);
        int2 p;
        p.x = ecol[j] | ((r & (RPB - 1)) << 17);     // col (17b) | row-low (9b)
        p.y = __float_as_int(eval[j]);
        tmp[pos] = p;
    }
}

// ---------------- pass C: per-bucket counting sort into final CSR pv ----------------
__global__ __launch_bounds__(256) void bucket_sort_kernel(const int2* __restrict__ tmp,
                                                          const int* __restrict__ row_start,
                                                          int2* __restrict__ pv, int n) {
    __shared__ int cur[RPB];
    int bkt = blockIdx.x;
    int r0 = bkt << 9;
    int r1 = min(n, r0 + RPB);
    for (int i = threadIdx.x; i < r1 - r0; i += 256) cur[i] = row_start[r0 + i];
    __syncthreads();
    int s = row_start[r0], e = row_start[r1];
    for (int j = s + threadIdx.x; j < e; j += 256) {
        int2 p = tmp[j];
        int pos = atomicAdd(&cur[p.x >> 17], 1);
        int2 q;
        q.x = p.x & 0x1FFFF;
        q.y = p.y;
        pv[pos] = q;
    }
}

// ---------------- pull-mode CSR SPMM (bf16 gather, bf16 out) ----------------
__global__ __launch_bounds__(256) void spmm_csr_kernel(const int* __restrict__ row_start,
                                                       const int2* __restrict__ pv,
                                                       const unsigned short* __restrict__ xb,
                                                       unsigned short* __restrict__ Lxb, int n) {
    int r = blockIdx.x * 8 + (threadIdx.x >> 5);
    if (r >= n) return;
    int l = threadIdx.x & 31;
    int s = row_start[r], e = row_start[r + 1];
    float a0 = 0.f, a1 = 0.f, a2 = 0.f, a3 = 0.f;
    int j = s;
    for (; j + 3 < e; j += 4) {
        int2 p0 = pv[j], p1 = pv[j + 1], p2 = pv[j + 2], p3 = pv[j + 3];
        float v0 = __int_as_float(p0.y), v1 = __int_as_float(p1.y);
        float v2 = __int_as_float(p2.y), v3 = __int_as_float(p3.y);
        ushort4 x0 = *reinterpret_cast<const ushort4*>(xb + (size_t)p0.x * ND + l * 4);
        ushort4 x1 = *reinterpret_cast<const ushort4*>(xb + (size_t)p1.x * ND + l * 4);
        ushort4 x2 = *reinterpret_cast<const ushort4*>(xb + (size_t)p2.x * ND + l * 4);
        ushort4 x3 = *reinterpret_cast<const ushort4*>(xb + (size_t)p3.x * ND + l * 4);
        a0 += v0 * bf2f(x0.x) + v1 * bf2f(x1.x) + v2 * bf2f(x2.x) + v3 * bf2f(x3.x);
        a1 += v0 * bf2f(x0.y) + v1 * bf2f(x1.y) + v2 * bf2f(x2.y) + v3 * bf2f(x3.y);
        a2 += v0 * bf2f(x0.z) + v1 * bf2f(x1.z) + v2 * bf2f(x2.z) + v3 * bf2f(x3.z);
        a3 += v0 * bf2f(x0.w) + v1 * bf2f(x1.w) + v2 * bf2f(x2.w) + v3 * bf2f(x3.w);
    }
    for (; j < e; ++j) {
        int2 p0 = pv[j];
        float v0 = __int_as_float(p0.y);
        ushort4 x0 = *reinterpret_cast<const ushort4*>(xb + (size_t)p0.x * ND + l * 4);
        a0 += v0 * bf2f(x0.x);
        a1 += v0 * bf2f(x0.y);
        a2 += v0 * bf2f(x0.z);
        a3 += v0 * bf2f(x0.w);
    }
    ushort4 o;
    o.x = (unsigned short)f2bf(a0); o.y = (unsigned short)f2bf(a1);
    o.z = (unsigned short)f2bf(a2); o.w = (unsigned short)f2bf(a3);
    *reinterpret_cast<ushort4*>(Lxb + (size_t)r * ND + l * 4) = o;
}

// ---------------- prep: Wt[layer][n][k] = bf16 of [Wgc;Wbi]^T, bsum = bgc+bbi ----------
__global__ void prep_w_kernel(const float* __restrict__ Wgc, const float* __restrict__ bgc,
                              const float* __restrict__ Wbi, const float* __restrict__ bbi,
                              short* __restrict__ Wt, float* __restrict__ bsum) {
    int z = blockIdx.x;
    int k = blockIdx.y;
    int t = threadIdx.x;
    int nn = t & 127;
    const float* src = (t < 128) ? (Wgc + ((size_t)z * 128 + k) * 128)
                                 : (Wbi + ((size_t)z * 128 + k) * 128);
    float v = src[nn];
    int kk = (t < 128) ? k : (128 + k);
    Wt[(size_t)z * 128 * 256 + (size_t)nn * 256 + kk] = f2bf(v);
    if (k == 0 && t < 128) bsum[z * 128 + t] = bgc[z * 128 + t] + bbi[z * 128 + t];
}

// ---------------- fused layer via MFMA (bf16 x + bf16 Lx inputs) ----------------
__global__ __launch_bounds__(256) void fused_layer_mfma(
        const unsigned short* __restrict__ xbin,  // [n][128] bf16 (current x)
        const unsigned short* __restrict__ Lxb,   // [n][128] bf16
        const short* __restrict__ Wt,             // [128][256] bf16 (W^T concat)
        const float* __restrict__ bsum,           // [128]
        float* __restrict__ xout,                 // row stride LDO (fp32 out slice)
        unsigned short* __restrict__ xbout,       // [n][128] bf16 shadow (next x)
        int n) {
    __shared__ short A_lds[64 * 256];    // 32 KB
    __shared__ short W_lds[128 * 128];   // 32 KB

    const int tid  = threadIdx.x;
    const int row0 = blockIdx.x * 64;
    const int lane = tid & 63;
    const int w    = tid >> 6;
    const int lrow = lane & 15;
    const int kgrp = lane >> 4;

    // ---- stage A = prop||xm, bf16, swizzled (16B units, ^ (row&7)) ----
#pragma unroll
    for (int t = 0; t < 4; ++t) {
        int idx = tid + t * 256;
        int r   = idx >> 4;              // 0..63
        int ck  = idx & 15;              // 8-elem chunk
        int grow = row0 + r;
        short8 xv8 = (short8){0,0,0,0,0,0,0,0};
        short8 lv8 = (short8){0,0,0,0,0,0,0,0};
        if (grow < n) {
            xv8 = *reinterpret_cast<const short8*>(xbin + (size_t)grow * ND + ck * 8);
            lv8 = *reinterpret_cast<const short8*>(Lxb + (size_t)grow * ND + ck * 8);
        }
        short8 pr, xm;
#pragma unroll
        for (int q = 0; q < 8; ++q) {
            float xf = bf2f((unsigned short)xv8[q]);
            float lf = bf2f((unsigned short)lv8[q]);
            pr[q] = f2bf(xf + lf);
            xm[q] = f2bf(xf * lf);
        }
        int s = r & 7;
        *reinterpret_cast<short8*>(&A_lds[r * 256 + ((ck        ^ s) << 3)]) = pr;
        *reinterpret_cast<short8*>(&A_lds[r * 256 + (((16 + ck) ^ s) << 3)]) = xm;
    }

    f32x4 acc[8];
#pragma unroll
    for (int nf = 0; nf < 8; ++nf) acc[nf] = (f32x4){0.f, 0.f, 0.f, 0.f};

#pragma unroll
    for (int h = 0; h < 2; ++h) {
        if (h) __syncthreads();
#pragma unroll
        for (int t = 0; t < 8; ++t) {
            int idx = tid + t * 256;
            int nr  = idx >> 4;
            int kkl = idx & 15;
            short8 wv = *reinterpret_cast<const short8*>(&Wt[(size_t)nr * 256 + h * 128 + kkl * 8]);
            *reinterpret_cast<short8*>(&W_lds[nr * 128 + ((kkl ^ (nr & 7)) << 3)]) = wv;
        }
        __syncthreads();

        const int ar = w * 16 + lrow;
        const int as = ar & 7;
#pragma unroll
        for (int ksl = 0; ksl < 4; ++ksl) {
            int kk  = h * 16 + ksl * 4 + kgrp;
            int kkl = ksl * 4 + kgrp;
            short8 af = *reinterpret_cast<const short8*>(&A_lds[ar * 256 + ((kk ^ as) << 3)]);
#pragma unroll
            for (int nf = 0; nf < 8; ++nf) {
                int nr = nf * 16 + lrow;
                short8 bfr = *reinterpret_cast<const short8*>(&W_lds[nr * 128 + ((kkl ^ (nr & 7)) << 3)]);
                acc[nf] = __builtin_amdgcn_mfma_f32_16x16x32_bf16(af, bfr, acc[nf], 0, 0, 0);
            }
        }
    }

    // ---- epilogue: bias + leaky + row l2-norm; write fp32 out + bf16 shadow ----
    float bsv[8];
#pragma unroll
    for (int nf = 0; nf < 8; ++nf) bsv[nf] = bsum[nf * 16 + lrow];

#pragma unroll
    for (int reg = 0; reg < 4; ++reg) {
        int grow = row0 + w * 16 + kgrp * 4 + reg;
        float v[8];
        float ssq = 0.f;
#pragma unroll
        for (int nf = 0; nf < 8; ++nf) {
            float tv = acc[nf][reg] + bsv[nf];
            tv = tv > 0.f ? tv : ALPHA * tv;
            v[nf] = tv;
            ssq += tv * tv;
        }
        ssq += __shfl_xor(ssq, 1);
        ssq += __shfl_xor(ssq, 2);
        ssq += __shfl_xor(ssq, 4);
        ssq += __shfl_xor(ssq, 8);
        float sc = 1.0f / sqrtf(fmaxf(ssq, L2EPS));
        if (grow < n) {
            float* op = xout + (size_t)grow * LDO;
            unsigned short* bp = xbout + (size_t)grow * ND;
#pragma unroll
            for (int nf = 0; nf < 8; ++nf) {
                float ov = v[nf] * sc;
                op[nf * 16 + lrow] = ov;
                bp[nf * 16 + lrow] = (unsigned short)f2bf(ov);
            }
        }
    }
}

extern "C" void kernel_launch(void* const* d_in, const int* in_sizes, int n_in,
                              void* d_out, int out_size, void* d_ws, size_t ws_size,
                              hipStream_t stream) {
    const float* emb  = (const float*)d_in[0];
    const int*   erow = (const int*)d_in[1];
    const int*   ecol = (const int*)d_in[2];
    const float* eval = (const float*)d_in[3];
    const float* Wgc  = (const float*)d_in[4];
    const float* bgc  = (const float*)d_in[5];
    const float* Wbi  = (const float*)d_in[6];
    const float* bbi  = (const float*)d_in[7];
    float* out = (float*)d_out;

    const int n        = in_sizes[0] / ND;      // 100000
    const int n_edges  = in_sizes[1];           // 1600000
    const int n_layers = in_sizes[5] / ND;      // 3

    const int nb = (n + RPB - 1) >> 9;          // 196 buckets
    const int ch = (n_edges + NCHUNK - 1) / NCHUNK;   // 6250 edges/chunk
    const int ng = nb * NCHUNK;                 // 50176

    // ---- workspace layout (256B-aligned) ----
    char* ws = (char*)d_ws;
    size_t off = 0;
    auto alloc = [&](size_t bytes) { void* p = ws + off; off = (off + bytes + 255) & ~(size_t)255; return p; };
    unsigned short* xb  = (unsigned short*)alloc((size_t)n * ND * sizeof(short));   // 25.6 MB
    unsigned short* Lxb = (unsigned short*)alloc((size_t)n * ND * sizeof(short));   // 25.6 MB
    int2*  pv        = (int2*) alloc((size_t)n_edges * sizeof(int2));               // 12.8 MB
    int2*  tmp       = (int2*) alloc((size_t)n_edges * sizeof(int2));               // 12.8 MB
    int*   counts    = (int*)  alloc((size_t)n * sizeof(int));
    int*   row_start = (int*)  alloc((size_t)(n + 1) * sizeof(int));
    int*   gcnt      = (int*)  alloc((size_t)ng * sizeof(int));
    int*   gbase     = (int*)  alloc((size_t)ng * sizeof(int));
    int*   partials  = (int*)  alloc(512 * sizeof(int));
    short* Wt        = (short*)alloc((size_t)n_layers * 128 * 256 * sizeof(short));
    float* bsum      = (float*)alloc((size_t)n_layers * 128 * sizeof(float));
    (void)ws_size;

    // ---- x0 -> out[:, 0:128] + xb ----
    {
        int total = n * 32;
        copy_emb_kernel<<<(total + 255) / 256, 256, 0, stream>>>(emb, out, xb, n);
    }

    // ---- weight prep ----
    {
        dim3 g(n_layers, 128);
        prep_w_kernel<<<g, 256, 0, stream>>>(Wgc, bgc, Wbi, bbi, Wt, bsum);
    }

    // ---- CSR build: histograms ----
    hipMemsetAsync(counts, 0, (size_t)n * sizeof(int), stream);
    bucket_hist_kernel<<<NCHUNK, 256, 0, stream>>>(erow, counts, gcnt, n_edges, nb, ch);

    // row_start = exscan(counts), sentinel n_edges
    {
        int nblk = (n + SCAN_B - 1) / SCAN_B;
        scanA_kernel<<<nblk, SCAN_B, 0, stream>>>(counts, row_start, partials, n);
        scanB_kernel<<<1, 512, 0, stream>>>(partials, nblk);
        scan_add_kernel<<<(n + 1 + 255) / 256, 256, 0, stream>>>(row_start, partials, n, n_edges, 1);
    }
    // gbase = exscan(gcnt)
    {
        int nblk = (ng + SCAN_B - 1) / SCAN_B;
        scanA_kernel<<<nblk, SCAN_B, 0, stream>>>(gcnt, gbase, partials, ng);
        scanB_kernel<<<1, 512, 0, stream>>>(partials, nblk);
        scan_add_kernel<<<(ng + 255) / 256, 256, 0, stream>>>(gbase, partials, ng, 0, 0);
    }

    // ---- pass B + C ----
    bucket_scatter_kernel<<<NCHUNK, 256, 0, stream>>>(erow, ecol, eval, gbase, tmp, n_edges, nb, ch);
    bucket_sort_kernel<<<nb, 256, 0, stream>>>(tmp, row_start, pv, n);

    // ---- layers ----
    for (int i = 0; i < n_layers; ++i) {
        spmm_csr_kernel<<<(n + 7) / 8, 256, 0, stream>>>(row_start, pv, xb, Lxb, n);
        fused_layer_mfma<<<(n + 63) / 64, 256, 0, stream>>>(
            xb, Lxb,
            Wt + (size_t)i * 128 * 256, bsum + (size_t)i * 128,
            out + (size_t)(i + 1) * ND, xb, n);
    }
}

// Round 6
// 401.100 us; speedup vs baseline: 21.7411x; 1.1193x over previous
//
#include <hip/hip_runtime.h>
#include <hip/hip_bf16.h>

#define ND 128
#define LDO 512
#define ALPHA 0.2f
#define L2EPS 1e-12f
#define SCAN_B 256
#define NCHUNK 256     // edge chunks for bucket hist/scatter
#define RPB 512        // rows per bucket (shift 9)

typedef __attribute__((ext_vector_type(8))) short short8;
typedef __attribute__((ext_vector_type(4))) float f32x4;

__device__ __forceinline__ short f2bf(float f) {
    union { float f; unsigned u; } c; c.f = f;
    unsigned u = c.u;
    unsigned r = (u + 0x7fffu + ((u >> 16) & 1u)) >> 16;   // RNE
    return (short)r;
}
__device__ __forceinline__ float bf2f(unsigned short u) {
    union { unsigned u; float f; } c; c.u = ((unsigned)u) << 16;
    return c.f;
}
__device__ __forceinline__ void gload_lds16(const void* g, void* l) {
    __builtin_amdgcn_global_load_lds(
        (const __attribute__((address_space(1))) unsigned int*)g,
        (__attribute__((address_space(3))) unsigned int*)l, 16, 0, 0);
}

// ---------------- copy embeddings into out[:, 0:128] and xb ----------------
__global__ void copy_emb_kernel(const float* __restrict__ emb, float* __restrict__ out,
                                unsigned short* __restrict__ xb, int n) {
    int idx = blockIdx.x * blockDim.x + threadIdx.x;
    int total = n * 32;
    if (idx >= total) return;
    int r = idx >> 5, c4 = idx & 31;
    const float4 v = *reinterpret_cast<const float4*>(emb + (size_t)r * ND + c4 * 4);
    *reinterpret_cast<float4*>(out + (size_t)r * LDO + c4 * 4) = v;
    ushort4 b;
    b.x = (unsigned short)f2bf(v.x); b.y = (unsigned short)f2bf(v.y);
    b.z = (unsigned short)f2bf(v.z); b.w = (unsigned short)f2bf(v.w);
    *reinterpret_cast<ushort4*>(xb + (size_t)r * ND + c4 * 4) = b;
}

// ---------------- pass A: per-chunk bucket histogram (LDS only) ----------------
__global__ __launch_bounds__(256) void bucket_hist_kernel(const int* __restrict__ erow,
                                                          int* __restrict__ gcnt,
                                                          int n_edges, int nb, int ch) {
    __shared__ int cnt[256];
    int b = blockIdx.x;
    cnt[threadIdx.x] = 0;
    __syncthreads();
    int s = b * ch, e = min(n_edges, s + ch);
    for (int j = s + threadIdx.x; j < e; j += 256) {
        atomicAdd(&cnt[erow[j] >> 9], 1);
    }
    __syncthreads();
    for (int i = threadIdx.x; i < nb; i += 256) gcnt[i * NCHUNK + b] = cnt[i];
}

// ---------------- scans ----------------
__global__ __launch_bounds__(SCAN_B) void scanA_kernel(const int* __restrict__ in,
                                                       int* __restrict__ outp,
                                                       int* __restrict__ partials, int n) {
    __shared__ int sm[SCAN_B];
    int i = blockIdx.x * SCAN_B + threadIdx.x;
    int v = (i < n) ? in[i] : 0;
    sm[threadIdx.x] = v;
    __syncthreads();
#pragma unroll
    for (int off = 1; off < SCAN_B; off <<= 1) {
        int t = (threadIdx.x >= off) ? sm[threadIdx.x - off] : 0;
        __syncthreads();
        sm[threadIdx.x] += t;
        __syncthreads();
    }
    if (i < n) outp[i] = sm[threadIdx.x] - v;
    if (threadIdx.x == SCAN_B - 1) partials[blockIdx.x] = sm[SCAN_B - 1];
}

__global__ __launch_bounds__(512) void scanB_kernel(int* __restrict__ partials, int nb) {
    __shared__ int sm[512];
    int v = (threadIdx.x < nb) ? partials[threadIdx.x] : 0;
    sm[threadIdx.x] = v;
    __syncthreads();
#pragma unroll
    for (int off = 1; off < 512; off <<= 1) {
        int t = (threadIdx.x >= off) ? sm[threadIdx.x - off] : 0;
        __syncthreads();
        sm[threadIdx.x] += t;
        __syncthreads();
    }
    if (threadIdx.x < nb) partials[threadIdx.x] = sm[threadIdx.x] - v;
}

__global__ void scan_add_kernel(int* __restrict__ arr, const int* __restrict__ partials, int n) {
    int i = blockIdx.x * blockDim.x + threadIdx.x;
    if (i < n) arr[i] += partials[i >> 8];
}

// ---------------- pass B: scatter into bucket-grouped tmp (coalesced runs) ----------------
__global__ __launch_bounds__(256) void bucket_scatter_kernel(const int* __restrict__ erow,
                                                             const int* __restrict__ ecol,
                                                             const float* __restrict__ eval,
                                                             const int* __restrict__ gbase,
                                                             int2* __restrict__ tmp,
                                                             int n_edges, int nb, int ch) {
    __shared__ int cur[256];
    int b = blockIdx.x;
    for (int i = threadIdx.x; i < nb; i += 256) cur[i] = gbase[i * NCHUNK + b];
    __syncthreads();
    int s = b * ch, e = min(n_edges, s + ch);
    for (int j = s + threadIdx.x; j < e; j += 256) {
        int r = erow[j];
        int pos = atomicAdd(&cur[r >> 9], 1);
        int2 p;
        p.x = ecol[j] | ((r & (RPB - 1)) << 17);     // col (17b) | row-low (9b)
        p.y = __float_as_int(eval[j]);
        tmp[pos] = p;
    }
}

// ---------------- pass C: per-bucket counting sort into final CSR pv + row_start ----------
__global__ __launch_bounds__(256) void bucket_sort_kernel(const int2* __restrict__ tmp,
                                                          const int* __restrict__ gbase,
                                                          int2* __restrict__ pv,
                                                          int* __restrict__ row_start,
                                                          int n, int n_edges, int nb) {
    __shared__ int hist[RPB];
    __shared__ int cur[RPB];
    __shared__ int sc[256];
    const int t = threadIdx.x;
    const int bkt = blockIdx.x;
    const int r0 = bkt << 9;
    const int s = gbase[bkt * NCHUNK];
    const int e = (bkt + 1 < nb) ? gbase[(bkt + 1) * NCHUNK] : n_edges;

    for (int i = t; i < RPB; i += 256) hist[i] = 0;
    __syncthreads();
    for (int j = s + t; j < e; j += 256) atomicAdd(&hist[tmp[j].x >> 17], 1);
    __syncthreads();
    // exclusive scan of hist[512] via pair-scan
    int a0 = hist[2 * t], a1 = hist[2 * t + 1];
    sc[t] = a0 + a1;
    __syncthreads();
#pragma unroll
    for (int off = 1; off < 256; off <<= 1) {
        int v = (t >= off) ? sc[t - off] : 0;
        __syncthreads();
        sc[t] += v;
        __syncthreads();
    }
    int base = s + sc[t] - a0 - a1;
    cur[2 * t] = base;
    cur[2 * t + 1] = base + a0;
    __syncthreads();
    // write row_start (global CSR offsets)
    int r1 = min(n, r0 + RPB);
    for (int i = t; i < r1 - r0; i += 256) row_start[r0 + i] = cur[i];
    if (t == 0 && r1 == n) row_start[n] = n_edges;
    __syncthreads();   // all row_start reads of cur done before scatter mutates
    // scatter within bucket
    for (int j = s + t; j < e; j += 256) {
        int2 p = tmp[j];
        int pos = atomicAdd(&cur[p.x >> 17], 1);
        int2 q;
        q.x = p.x & 0x1FFFF;
        q.y = p.y;
        pv[pos] = q;
    }
}

// ---------------- SPMM + prop/xm formation, pre-swizzled bf16 Axm ----------------
// 32 lanes per row; Axm row = 512B = [pr(16 chunks) | xm(16 chunks)], chunk c stored at (c^(r&7))
__global__ __launch_bounds__(256) void spmm_axm_kernel(const int* __restrict__ row_start,
                                                       const int2* __restrict__ pv,
                                                       const unsigned short* __restrict__ xb,
                                                       unsigned short* __restrict__ Axm, int n) {
    int r = blockIdx.x * 8 + (threadIdx.x >> 5);
    if (r >= n) return;
    int l = threadIdx.x & 31;
    int s = row_start[r], e = row_start[r + 1];
    float a0 = 0.f, a1 = 0.f, a2 = 0.f, a3 = 0.f;
    int j = s;
    for (; j + 3 < e; j += 4) {
        int2 p0 = pv[j], p1 = pv[j + 1], p2 = pv[j + 2], p3 = pv[j + 3];
        float v0 = __int_as_float(p0.y), v1 = __int_as_float(p1.y);
        float v2 = __int_as_float(p2.y), v3 = __int_as_float(p3.y);
        ushort4 x0 = *reinterpret_cast<const ushort4*>(xb + (size_t)p0.x * ND + l * 4);
        ushort4 x1 = *reinterpret_cast<const ushort4*>(xb + (size_t)p1.x * ND + l * 4);
        ushort4 x2 = *reinterpret_cast<const ushort4*>(xb + (size_t)p2.x * ND + l * 4);
        ushort4 x3 = *reinterpret_cast<const ushort4*>(xb + (size_t)p3.x * ND + l * 4);
        a0 += v0 * bf2f(x0.x) + v1 * bf2f(x1.x) + v2 * bf2f(x2.x) + v3 * bf2f(x3.x);
        a1 += v0 * bf2f(x0.y) + v1 * bf2f(x1.y) + v2 * bf2f(x2.y) + v3 * bf2f(x3.y);
        a2 += v0 * bf2f(x0.z) + v1 * bf2f(x1.z) + v2 * bf2f(x2.z) + v3 * bf2f(x3.z);
        a3 += v0 * bf2f(x0.w) + v1 * bf2f(x1.w) + v2 * bf2f(x2.w) + v3 * bf2f(x3.w);
    }
    for (; j < e; ++j) {
        int2 p0 = pv[j];
        float v0 = __int_as_float(p0.y);
        ushort4 x0 = *reinterpret_cast<const ushort4*>(xb + (size_t)p0.x * ND + l * 4);
        a0 += v0 * bf2f(x0.x);
        a1 += v0 * bf2f(x0.y);
        a2 += v0 * bf2f(x0.z);
        a3 += v0 * bf2f(x0.w);
    }
    // x row (own row, streaming)
    ushort4 xv = *reinterpret_cast<const ushort4*>(xb + (size_t)r * ND + l * 4);
    float x0 = bf2f(xv.x), x1 = bf2f(xv.y), x2 = bf2f(xv.z), x3 = bf2f(xv.w);
    ushort4 prv, xmv;
    prv.x = (unsigned short)f2bf(x0 + a0); prv.y = (unsigned short)f2bf(x1 + a1);
    prv.z = (unsigned short)f2bf(x2 + a2); prv.w = (unsigned short)f2bf(x3 + a3);
    xmv.x = (unsigned short)f2bf(x0 * a0); xmv.y = (unsigned short)f2bf(x1 * a1);
    xmv.z = (unsigned short)f2bf(x2 * a2); xmv.w = (unsigned short)f2bf(x3 * a3);
    int sz = r & 7, ck = l >> 1, lo = (l & 1) * 4;
    unsigned short* rowp = Axm + (size_t)r * 256;
    *reinterpret_cast<ushort4*>(rowp + (((ck)      ^ sz) << 3) + lo) = prv;
    *reinterpret_cast<ushort4*>(rowp + (((16 + ck) ^ sz) << 3) + lo) = xmv;
}

// ---------------- prep: Wt2[layer][h][nr][..] pre-swizzled bf16, bsum = bgc+bbi ----------
__global__ void prep_w_kernel(const float* __restrict__ Wgc, const float* __restrict__ bgc,
                              const float* __restrict__ Wbi, const float* __restrict__ bbi,
                              short* __restrict__ Wt2, float* __restrict__ bsum) {
    int z = blockIdx.x;
    int k = blockIdx.y;            // K index within half, 0..127
    int t = threadIdx.x;
    int nn = t & 127;              // N index
    int h  = (t < 128) ? 0 : 1;    // half 0 = Wgc (prop), 1 = Wbi (xm)
    const float* src = h ? (Wbi + ((size_t)z * 128 + k) * 128)
                         : (Wgc + ((size_t)z * 128 + k) * 128);
    float v = src[nn];
    int idx16 = k >> 3, e8 = k & 7;
    size_t addr = ((size_t)(z * 2 + h) * 128 + nn) * 128 + ((idx16 ^ (nn & 7)) << 3) + e8;
    Wt2[addr] = f2bf(v);
    if (k == 0 && t < 128) bsum[z * 128 + t] = bgc[z * 128 + t] + bbi[z * 128 + t];
}

// ---------------- fused layer via MFMA (pure-copy staging) ----------------
__global__ __launch_bounds__(256) void fused_layer_mfma(
        const unsigned short* __restrict__ Axm,   // [(n+pad)][256] pre-swizzled
        const short* __restrict__ Wt2,            // [2][128][128] pre-swizzled (layer base)
        const float* __restrict__ bsum,           // [128]
        float* __restrict__ xout,                 // row stride LDO (fp32 out slice)
        unsigned short* __restrict__ xbout,       // [n][128] bf16 shadow (next x)
        int n) {
    __shared__ short A_lds[64 * 256];    // 32 KB
    __shared__ short W_lds[128 * 128];   // 32 KB

    const int tid  = threadIdx.x;
    const int row0 = blockIdx.x * 64;
    const int lane = tid & 63;
    const int w    = tid >> 6;
    const int lrow = lane & 15;
    const int kgrp = lane >> 4;

    // ---- async stage: A tile (32KB) + W half 0 (32KB), both LDS-linear copies ----
    {
        const char* gA = (const char*)(Axm + (size_t)row0 * 256) + w * 8192 + lane * 16;
        char*       lA = (char*)A_lds + w * 8192;
        const char* gW = (const char*)Wt2 + w * 8192 + lane * 16;
        char*       lW = (char*)W_lds + w * 8192;
#pragma unroll
        for (int it = 0; it < 8; ++it) {
            gload_lds16(gA + it * 1024, lA + it * 1024);
            gload_lds16(gW + it * 1024, lW + it * 1024);
        }
    }
    asm volatile("s_waitcnt vmcnt(0)" ::: "memory");
    __syncthreads();

    f32x4 acc[8];
#pragma unroll
    for (int nf = 0; nf < 8; ++nf) acc[nf] = (f32x4){0.f, 0.f, 0.f, 0.f};

    const int ar  = w * 16 + lrow;
    const int as_ = ar & 7;

    // ---- half 0 (prop @ Wgc) ----
#pragma unroll
    for (int ksl = 0; ksl < 4; ++ksl) {
        int kkl = ksl * 4 + kgrp;                    // 0..15
        short8 af = *reinterpret_cast<const short8*>(&A_lds[ar * 256 + ((kkl ^ as_) << 3)]);
#pragma unroll
        for (int nf = 0; nf < 8; ++nf) {
            int nr = nf * 16 + lrow;
            short8 bfr = *reinterpret_cast<const short8*>(&W_lds[nr * 128 + ((kkl ^ (nr & 7)) << 3)]);
            acc[nf] = __builtin_amdgcn_mfma_f32_16x16x32_bf16(af, bfr, acc[nf], 0, 0, 0);
        }
    }
    __syncthreads();
    // ---- stage W half 1 ----
    {
        const char* gW = (const char*)Wt2 + 32768 + w * 8192 + lane * 16;
        char*       lW = (char*)W_lds + w * 8192;
#pragma unroll
        for (int it = 0; it < 8; ++it) gload_lds16(gW + it * 1024, lW + it * 1024);
    }
    asm volatile("s_waitcnt vmcnt(0)" ::: "memory");
    __syncthreads();

    // ---- half 1 (xm @ Wbi) ----
#pragma unroll
    for (int ksl = 0; ksl < 4; ++ksl) {
        int kkl = ksl * 4 + kgrp;
        short8 af = *reinterpret_cast<const short8*>(&A_lds[ar * 256 + (((16 + kkl) ^ as_) << 3)]);
#pragma unroll
        for (int nf = 0; nf < 8; ++nf) {
            int nr = nf * 16 + lrow;
            short8 bfr = *reinterpret_cast<const short8*>(&W_lds[nr * 128 + ((kkl ^ (nr & 7)) << 3)]);
            acc[nf] = __builtin_amdgcn_mfma_f32_16x16x32_bf16(af, bfr, acc[nf], 0, 0, 0);
        }
    }

    // ---- epilogue: bias + leaky + row l2-norm; write fp32 out + bf16 shadow ----
    float bsv[8];
#pragma unroll
    for (int nf = 0; nf < 8; ++nf) bsv[nf] = bsum[nf * 16 + lrow];

#pragma unroll
    for (int reg = 0; reg < 4; ++reg) {
        int grow = row0 + w * 16 + kgrp * 4 + reg;
        float v[8];
        float ssq = 0.f;
#pragma unroll
        for (int nf = 0; nf < 8; ++nf) {
            float tv = acc[nf][reg] + bsv[nf];
            tv = tv > 0.f ? tv : ALPHA * tv;
            v[nf] = tv;
            ssq += tv * tv;
        }
        ssq += __shfl_xor(ssq, 1);
        ssq += __shfl_xor(ssq, 2);
        ssq += __shfl_xor(ssq, 4);
        ssq += __shfl_xor(ssq, 8);
        float sc = 1.0f / sqrtf(fmaxf(ssq, L2EPS));
        if (grow < n) {
            float* op = xout + (size_t)grow * LDO;
            unsigned short* bp = xbout + (size_t)grow * ND;
#pragma unroll
            for (int nf = 0; nf < 8; ++nf) {
                float ov = v[nf] * sc;
                op[nf * 16 + lrow] = ov;
                bp[nf * 16 + lrow] = (unsigned short)f2bf(ov);
            }
        }
    }
}

extern "C" void kernel_launch(void* const* d_in, const int* in_sizes, int n_in,
                              void* d_out, int out_size, void* d_ws, size_t ws_size,
                              hipStream_t stream) {
    const float* emb  = (const float*)d_in[0];
    const int*   erow = (const int*)d_in[1];
    const int*   ecol = (const int*)d_in[2];
    const float* eval = (const float*)d_in[3];
    const float* Wgc  = (const float*)d_in[4];
    const float* bgc  = (const float*)d_in[5];
    const float* Wbi  = (const float*)d_in[6];
    const float* bbi  = (const float*)d_in[7];
    float* out = (float*)d_out;

    const int n        = in_sizes[0] / ND;      // 100000
    const int n_edges  = in_sizes[1];           // 1600000
    const int n_layers = in_sizes[5] / ND;      // 3

    const int nb = (n + RPB - 1) >> 9;          // 196 buckets
    const int ch = (n_edges + NCHUNK - 1) / NCHUNK;   // edges per chunk
    const int ng = nb * NCHUNK;

    // ---- workspace layout (256B-aligned) ----
    char* ws = (char*)d_ws;
    size_t off = 0;
    auto alloc = [&](size_t bytes) { void* p = ws + off; off = (off + bytes + 255) & ~(size_t)255; return p; };
    unsigned short* xb  = (unsigned short*)alloc((size_t)n * ND * sizeof(short));        // 25.6 MB
    unsigned short* Axm = (unsigned short*)alloc((size_t)(n + 64) * 256 * sizeof(short)); // 51.2 MB (+pad)
    int2*  pv        = (int2*) alloc((size_t)n_edges * sizeof(int2));                    // 12.8 MB
    int2*  tmp       = (int2*) alloc((size_t)n_edges * sizeof(int2));                    // 12.8 MB
    int*   row_start = (int*)  alloc((size_t)(n + 1) * sizeof(int));
    int*   gcnt      = (int*)  alloc((size_t)ng * sizeof(int));
    int*   gbase     = (int*)  alloc((size_t)ng * sizeof(int));
    int*   partials  = (int*)  alloc(512 * sizeof(int));
    short* Wt2       = (short*)alloc((size_t)n_layers * 2 * 128 * 128 * sizeof(short));
    float* bsum      = (float*)alloc((size_t)n_layers * 128 * sizeof(float));
    (void)ws_size;

    // ---- x0 -> out[:, 0:128] + xb ----
    {
        int total = n * 32;
        copy_emb_kernel<<<(total + 255) / 256, 256, 0, stream>>>(emb, out, xb, n);
    }

    // ---- weight prep ----
    {
        dim3 g(n_layers, 128);
        prep_w_kernel<<<g, 256, 0, stream>>>(Wgc, bgc, Wbi, bbi, Wt2, bsum);
    }

    // ---- CSR build ----
    bucket_hist_kernel<<<NCHUNK, 256, 0, stream>>>(erow, gcnt, n_edges, nb, ch);
    {
        int nblk = (ng + SCAN_B - 1) / SCAN_B;
        scanA_kernel<<<nblk, SCAN_B, 0, stream>>>(gcnt, gbase, partials, ng);
        scanB_kernel<<<1, 512, 0, stream>>>(partials, nblk);
        scan_add_kernel<<<(ng + 255) / 256, 256, 0, stream>>>(gbase, partials, ng);
    }
    bucket_scatter_kernel<<<NCHUNK, 256, 0, stream>>>(erow, ecol, eval, gbase, tmp, n_edges, nb, ch);
    bucket_sort_kernel<<<nb, 256, 0, stream>>>(tmp, gbase, pv, row_start, n, n_edges, nb);

    // ---- layers ----
    for (int i = 0; i < n_layers; ++i) {
        spmm_axm_kernel<<<(n + 7) / 8, 256, 0, stream>>>(row_start, pv, xb, Axm, n);
        fused_layer_mfma<<<(n + 63) / 64, 256, 0, stream>>>(
            Axm, Wt2 + (size_t)i * 2 * 128 * 128, bsum + (size_t)i * 128,
            out + (size_t)(i + 1) * ND, xb, n);
    }
}